// Round 2
// baseline (9.377 us; speedup 1.0000x reference)
//
#include <hip/hip_runtime.h>

#define N_CLASSES 10
#define OUT_LEN (2 * N_CLASSES - 1)  // 19

// One wave, no LDS, no barriers. Every lane redundantly computes both
// softmaxes (loads broadcast from L1), then lanes 0..18 each write one
// convolution output. Problem is launch-overhead bound; minimize latency.
__global__ void __launch_bounds__(64)
sum_layer_kernel(const float* __restrict__ d0,
                 const float* __restrict__ d1,
                 float* __restrict__ out) {
    const int t = threadIdx.x;

    float a0[N_CLASSES], a1[N_CLASSES];
    float m0 = -INFINITY, m1 = -INFINITY;
#pragma unroll
    for (int i = 0; i < N_CLASSES; ++i) {
        a0[i] = d0[i];
        a1[i] = d1[i];
        m0 = fmaxf(m0, a0[i]);
        m1 = fmaxf(m1, a1[i]);
    }
    float s0 = 0.f, s1 = 0.f;
#pragma unroll
    for (int i = 0; i < N_CLASSES; ++i) {
        a0[i] = expf(a0[i] - m0);
        a1[i] = expf(a1[i] - m1);
        s0 += a0[i];
        s1 += a1[i];
    }
    const float r0 = 1.f / s0, r1 = 1.f / s1;

    if (t < OUT_LEN) {
        // out[t] = sum_{i+j=t} p0[i] * p1[j]
        const int ilo = t - (N_CLASSES - 1) > 0 ? t - (N_CLASSES - 1) : 0;
        const int ihi = t < (N_CLASSES - 1) ? t : (N_CLASSES - 1);
        float acc = 0.f;
        for (int i = ilo; i <= ihi; ++i) {
            acc += a0[i] * a1[t - i];
        }
        out[t] = acc * (r0 * r1);
    }
}

extern "C" void kernel_launch(void* const* d_in, const int* in_sizes, int n_in,
                              void* d_out, int out_size, void* d_ws, size_t ws_size,
                              hipStream_t stream) {
    const float* d0 = (const float*)d_in[0];
    const float* d1 = (const float*)d_in[1];
    float* out = (float*)d_out;
    sum_layer_kernel<<<1, 64, 0, stream>>>(d0, d1, out);
}

// Round 3
// 9.355 us; speedup vs baseline: 1.0024x; 1.0024x over previous
//
#include <hip/hip_runtime.h>

#define N_CLASSES 10
#define OUT_LEN (2 * N_CLASSES - 1)  // 19
#define LOG2E 1.4426950408889634f

// One wave, one block, no LDS, no barriers. Every lane redundantly computes
// both 10-element softmaxes in registers (vector loads, v_exp_f32 via exp2f),
// then lanes 0..18 each write one full-convolution output:
//   out[s] = sum_{i+j=s} p0[i] * p1[j]
// Problem is launch-overhead bound; this minimizes the in-kernel serial chain.
__global__ void __launch_bounds__(64)
sum_layer_kernel(const float* __restrict__ d0,
                 const float* __restrict__ d1,
                 float* __restrict__ out) {
    const int t = threadIdx.x;

    // Vectorized 40B loads: float4 + float4 + float2 per input.
    float a0[N_CLASSES], a1[N_CLASSES];
    {
        float4 v0a = *(const float4*)(d0);
        float4 v0b = *(const float4*)(d0 + 4);
        float2 v0c = *(const float2*)(d0 + 8);
        a0[0] = v0a.x; a0[1] = v0a.y; a0[2] = v0a.z; a0[3] = v0a.w;
        a0[4] = v0b.x; a0[5] = v0b.y; a0[6] = v0b.z; a0[7] = v0b.w;
        a0[8] = v0c.x; a0[9] = v0c.y;
        float4 v1a = *(const float4*)(d1);
        float4 v1b = *(const float4*)(d1 + 4);
        float2 v1c = *(const float2*)(d1 + 8);
        a1[0] = v1a.x; a1[1] = v1a.y; a1[2] = v1a.z; a1[3] = v1a.w;
        a1[4] = v1b.x; a1[5] = v1b.y; a1[6] = v1b.z; a1[7] = v1b.w;
        a1[8] = v1c.x; a1[9] = v1c.y;
    }

    float m0 = a0[0], m1 = a1[0];
#pragma unroll
    for (int i = 1; i < N_CLASSES; ++i) {
        m0 = fmaxf(m0, a0[i]);
        m1 = fmaxf(m1, a1[i]);
    }
    float s0 = 0.f, s1 = 0.f;
#pragma unroll
    for (int i = 0; i < N_CLASSES; ++i) {
        // exp(x-m) == exp2((x-m)*log2e): single v_exp_f32, same value.
        a0[i] = exp2f((a0[i] - m0) * LOG2E);
        a1[i] = exp2f((a1[i] - m1) * LOG2E);
        s0 += a0[i];
        s1 += a1[i];
    }
    const float rr = (1.f / s0) * (1.f / s1);

    if (t < OUT_LEN) {
        const int ilo = t - (N_CLASSES - 1) > 0 ? t - (N_CLASSES - 1) : 0;
        const int ihi = t < (N_CLASSES - 1) ? t : (N_CLASSES - 1);
        float acc = 0.f;
        for (int i = ilo; i <= ihi; ++i) {
            acc += a0[i] * a1[t - i];
        }
        out[t] = acc * rr;
    }
}

extern "C" void kernel_launch(void* const* d_in, const int* in_sizes, int n_in,
                              void* d_out, int out_size, void* d_ws, size_t ws_size,
                              hipStream_t stream) {
    const float* d0 = (const float*)d_in[0];
    const float* d1 = (const float*)d_in[1];
    float* out = (float*)d_out;
    sum_layer_kernel<<<1, 64, 0, stream>>>(d0, d1, out);
}